// Round 7
// baseline (187.923 us; speedup 1.0000x reference)
//
#include <hip/hip_runtime.h>
#include <hip/hip_bf16.h>

typedef _Float16 half8 __attribute__((ext_vector_type(8)));
typedef unsigned short ushort8 __attribute__((ext_vector_type(8)));
typedef float floatx4 __attribute__((ext_vector_type(4)));

#define B_ 4
#define C_ 256
#define N_ 4096
#define NT 32            // 128-wide tiles per dim
#define TRI 528          // NT*(NT+1)/2 triangular tiles per batch

// workspace layout (bytes)
#define OFF_FN    ((size_t)0)                     // 4*4096*256 fp16 = 8 MB
#define OFF_PROB  ((size_t)(8u << 20))            // 16384 fp32 = 64 KB
#define OFF_PART  (OFF_PROB + 65536)              // 4096 fp32 block partials = 16 KB
#define OFF_TOP   ((size_t)(16u << 20))           // 16384 rows x 32 jtiles x 8 u32 = 16 MB

__device__ __forceinline__ void gl_lds16(const void* g, void* l) {
    __builtin_amdgcn_global_load_lds(
        (const __attribute__((address_space(1))) void*)g,
        (__attribute__((address_space(3))) void*)l,
        16, 0, 0);
}

__device__ __forceinline__ void cas(uint32_t& a, uint32_t& b) {
    uint32_t hi = max(a, b); b = min(a, b); a = hi;
}

// Batcher odd-even mergesort, 8 elems, descending (19 CAS)
__device__ __forceinline__ void sort8(uint32_t v[8]) {
    cas(v[0],v[1]); cas(v[2],v[3]); cas(v[4],v[5]); cas(v[6],v[7]);
    cas(v[0],v[2]); cas(v[1],v[3]); cas(v[4],v[6]); cas(v[5],v[7]);
    cas(v[1],v[2]); cas(v[5],v[6]);
    cas(v[0],v[4]); cas(v[1],v[5]); cas(v[2],v[6]); cas(v[3],v[7]);
    cas(v[2],v[4]); cas(v[3],v[5]);
    cas(v[1],v[2]); cas(v[3],v[4]); cas(v[5],v[6]);
}

// r, n desc-sorted -> r = top-8 of union, desc-sorted (8 max + 12 CAS)
__device__ __forceinline__ void merge8(uint32_t r[8], const uint32_t n[8]) {
    uint32_t m[8];
#pragma unroll
    for (int i = 0; i < 8; ++i) m[i] = max(r[i], n[7 - i]);   // bitonic
    cas(m[0],m[4]); cas(m[1],m[5]); cas(m[2],m[6]); cas(m[3],m[7]);
    cas(m[0],m[2]); cas(m[1],m[3]); cas(m[4],m[6]); cas(m[5],m[7]);
    cas(m[0],m[1]); cas(m[2],m[3]); cas(m[4],m[5]); cas(m[6],m[7]);
#pragma unroll
    for (int i = 0; i < 8; ++i) r[i] = m[i];
}

// ---------------- Kernel 1: fused prep — reads feats once ----------------
#define TS 68
__global__ __launch_bounds__(256) void prep_kernel(const float* __restrict__ feats,
                                                   const float* __restrict__ logits,
                                                   _Float16* __restrict__ fn,
                                                   float* __restrict__ prob) {
    __shared__ __align__(16) float T[C_ * TS];
    __shared__ float S[256];
    __shared__ float I[64];

    const int t  = threadIdx.x;
    const int b  = blockIdx.x >> 6;
    const int i0 = (blockIdx.x & 63) * 64;
    const float* fb = feats + (size_t)b * C_ * N_;

#pragma unroll
    for (int k = 0; k < 16; ++k) {
        int ch = t + k * 256;
        int row = ch >> 4, col4 = ch & 15;
        float4 v = *(const float4*)(fb + (size_t)row * N_ + i0 + col4 * 4);
        *(float4*)&T[row * TS + col4 * 4] = v;
    }
    __syncthreads();
    {
        int i = t & 63, cq = t >> 6;
        float ss = 0.f;
#pragma unroll 8
        for (int j = 0; j < 64; ++j) { float v = T[(cq * 64 + j) * TS + i]; ss += v * v; }
        S[cq * 64 + i] = ss;
    }
    __syncthreads();
    if (t < 64) {
        float ss = S[t] + S[64 + t] + S[128 + t] + S[192 + t];
        I[t] = 1.f / fmaxf(sqrtf(ss), 1e-12f);
        float lg = logits[b * N_ + i0 + t];
        prob[b * N_ + i0 + t] = 1.f / (1.f + expf(-lg));
    }
    __syncthreads();
    {
        int i = t >> 2, chunk = t & 3;
        float s = I[i];
        _Float16* fr = fn + ((size_t)(b * N_ + i0 + i)) * C_ + chunk * 64;
#pragma unroll
        for (int v8 = 0; v8 < 8; ++v8) {
            half8 h;
#pragma unroll
            for (int e = 0; e < 8; ++e)
                h[e] = (_Float16)(T[(chunk * 64 + v8 * 8 + e) * TS + i] * s);
            *(half8*)(fr + v8 * 8) = h;
        }
    }
}

// ---------------- Kernel 2: triangular MFMA gram tile + dual-scan top-8 ----------------
// R5-proven structure (45.2 µs): BK=64 single-buffer K-loop, 64x64 wave quadrants,
// XCD swizzle. Templated for this round's ABLATION PROBES (launched post-`final`,
// overwrite only the dead `top` buffer):
//   MODE 0: production (full).
//   MODE 1: K-loop + dump only (GEMM/staging floor), asm-keepalive readback.
//   MODE 2: col path only (row-scan compiled out via diag=true).
#define CSH 136   // u16 col stride: 272B -> b128-aligned, window starts spread over banks
template <int MODE>
__global__ __launch_bounds__(256, 4) void gram_sel_t(const _Float16* __restrict__ fn,
                                                     uint32_t* __restrict__ top) {
    __shared__ __align__(16) char smem[128 * CSH * 2];   // 34816 B
    _Float16* As = (_Float16*)smem;                      // 16 KB (K-loop)
    _Float16* Bs = (_Float16*)(smem + 16384);            // 16 KB (K-loop)
    unsigned short* Ch = (unsigned short*)smem;          // col-major u16 tile (selection)
    uint32_t* Ms = (uint32_t*)smem;                      // pair-merge staging

    const int t    = threadIdx.x;
    const int lane = t & 63;
    const int w    = t >> 6;
    const int m16  = lane & 15;
    const int q    = lane >> 4;
    const int wm   = w & 1;          // row half (0..1)
    const int wn   = w >> 1;         // col half (0..1)

    // XCD-aware bijective swizzle: grid 2112 = 8 * 264
    const int bid0 = blockIdx.x;
    const int bid  = (bid0 & 7) * 264 + (bid0 >> 3);

    // triangular block index -> (b, it, jt) with it <= jt
    const int b = bid / TRI;
    const int u = bid - b * TRI;
    int it = (int)(32.5f - sqrtf(32.5f * 32.5f - 2.0f * (float)u));
    while (u >= (it + 1) * (65 - (it + 1)) / 2) ++it;
    while (u < it * (65 - it) / 2) --it;
    const int jt = it + (u - it * (65 - it) / 2);
    const bool diag = (MODE == 2) ? true : (it == jt);

    const int i0 = it * 128, j0 = jt * 128;
    const _Float16* fnb = fn + (size_t)b * N_ * C_;

    const int srowb = t >> 3;
    const int schunk = (t & 7) ^ (srowb & 7);
    const int sw = m16 & 7;

    floatx4 acc[4][4];
#pragma unroll
    for (int mi = 0; mi < 4; ++mi)
#pragma unroll
        for (int ni = 0; ni < 4; ++ni) acc[mi][ni] = floatx4{0.f, 0.f, 0.f, 0.f};

    for (int kc = 0; kc < 4; ++kc) {
#pragma unroll
        for (int r = 0; r < 4; ++r) {
            int row = r * 32 + srowb;
            const _Float16* gA = fnb + (size_t)(i0 + row) * C_ + kc * 64 + schunk * 8;
            const _Float16* gB = fnb + (size_t)(j0 + row) * C_ + kc * 64 + schunk * 8;
            gl_lds16(gA, (char*)As + r * 4096 + t * 16);
            gl_lds16(gB, (char*)Bs + r * 4096 + t * 16);
        }
        __syncthreads();
#pragma unroll
        for (int kk = 0; kk < 2; ++kk) {
            const int ko = ((kk * 4 + q) ^ sw) * 8;
            half8 af[4], bf[4];
#pragma unroll
            for (int mi = 0; mi < 4; ++mi)
                af[mi] = *(const half8*)&As[(wm * 64 + mi * 16 + m16) * 64 + ko];
#pragma unroll
            for (int ni = 0; ni < 4; ++ni)
                bf[ni] = *(const half8*)&Bs[(wn * 64 + ni * 16 + m16) * 64 + ko];
#pragma unroll
            for (int mi = 0; mi < 4; ++mi)
#pragma unroll
                for (int ni = 0; ni < 4; ++ni)
                    acc[mi][ni] = __builtin_amdgcn_mfma_f32_16x16x32_f16(af[mi], bf[ni], acc[mi][ni], 0, 0, 0);
        }
        __syncthreads();
    }

    // ---- dump tile col-major as flipped u16, paired rows via cvt_pkrtz ----
    // C/D layout: col = wn*64 + ni*16 + m16, rows = wm*64 + mi*16 + q*4 + {0..3}
#pragma unroll
    for (int ni = 0; ni < 4; ++ni)
#pragma unroll
        for (int mi = 0; mi < 4; ++mi) {
            const int col = wn * 64 + ni * 16 + m16;
            const int row = wm * 64 + mi * 16 + q * 4;
#pragma unroll
            for (int p = 0; p < 2; ++p) {
                auto pk2 = __builtin_amdgcn_cvt_pkrtz(acc[mi][ni][2 * p], acc[mi][ni][2 * p + 1]);
                uint32_t bits = __builtin_bit_cast(uint32_t, pk2);
                uint32_t s = (bits >> 15) & 0x00010001u;
                uint32_t fl = bits ^ (s * 0x7FFFu + 0x80008000u);   // per-half order-flip
                *(uint32_t*)&Ch[col * CSH + row + 2 * p] = fl;
            }
        }
    __syncthreads();

    if constexpr (MODE == 1) {
        // keepalive: read back one word/thread so the dump (and the MFMAs feeding
        // it) can't be DCE'd (rule #17); one store/thread to the dead top buffer.
        uint32_t v = *(uint32_t*)&Ch[t * 2];
        asm volatile("" :: "v"(v));
        top[(size_t)bid0 * 256 + t] = v;
        return;
    }

    // ---- contiguous col-scan (always): 2 threads/col, 64 rows each, b128 reads ----
    // packed idx = global ROW index. Off-diag: j-side partials; diag: == row result.
    uint32_t cpk[8], rpk[8];
    {
        const int ccol = t >> 1, cr0 = (t & 1) * 64;
        const unsigned short* cc = &Ch[ccol * CSH + cr0];
        const int ibase = i0 + cr0;
#pragma unroll
        for (int g = 0; g < 8; ++g) {
            ushort8 v = *(const ushort8*)(cc + g * 8);
            uint32_t cand[8];
#pragma unroll
            for (int e = 0; e < 8; ++e)
                cand[e] = ((uint32_t)v[e] << 16) | (uint32_t)(ibase + g * 8 + e);
            sort8(cand);
            if (g == 0) {
#pragma unroll
                for (int s = 0; s < 8; ++s) cpk[s] = cand[s];
            } else merge8(cpk, cand);
        }
    }
    // ---- strided row-scan (off-diag only): 2 threads/row, 64 cols each ----
    if (!diag) {
        const int rrow = t >> 1, ch0 = (t & 1) * 64;
        const unsigned short* cr = &Ch[ch0 * CSH + rrow];
        const int jbase = j0 + ch0;
#pragma unroll
        for (int g = 0; g < 8; ++g) {
            uint32_t cand[8];
#pragma unroll
            for (int e = 0; e < 8; ++e)
                cand[e] = ((uint32_t)cr[(g * 8 + e) * CSH] << 16) | (uint32_t)(jbase + g * 8 + e);
            sort8(cand);
            if (g == 0) {
#pragma unroll
                for (int s = 0; s < 8; ++s) rpk[s] = cand[s];
            } else merge8(rpk, cand);
        }
    }
    __syncthreads();   // done reading Ch; reuse as merge staging

    // ---- pair-merge across the 2 threads of each col/row, emit 8 u32 ----
    if (t & 1) {
#pragma unroll
        for (int s = 0; s < 8; ++s) Ms[(t >> 1) * 8 + s] = cpk[s];
        if (!diag) {
#pragma unroll
            for (int s = 0; s < 8; ++s) Ms[1024 + (t >> 1) * 8 + s] = rpk[s];
        }
    }
    __syncthreads();
    if (!(t & 1)) {
        uint32_t o[8];
#pragma unroll
        for (int s = 0; s < 8; ++s) o[s] = Ms[(t >> 1) * 8 + s];
        merge8(cpk, o);
        uint32_t* dst = top + (((size_t)b * N_ + j0 + (t >> 1)) * 32 + it) * 8;
        *(uint4*)dst       = make_uint4(cpk[0], cpk[1], cpk[2], cpk[3]);
        *(uint4*)(dst + 4) = make_uint4(cpk[4], cpk[5], cpk[6], cpk[7]);
        if (!diag) {
#pragma unroll
            for (int s = 0; s < 8; ++s) o[s] = Ms[1024 + (t >> 1) * 8 + s];
            merge8(rpk, o);
            uint32_t* dst2 = top + (((size_t)b * N_ + i0 + (t >> 1)) * 32 + jt) * 8;
            *(uint4*)dst2       = make_uint4(rpk[0], rpk[1], rpk[2], rpk[3]);
            *(uint4*)(dst2 + 4) = make_uint4(rpk[4], rpk[5], rpk[6], rpk[7]);
        }
    }
}

// ---------------- Kernel 3: merge 32 partials/row, gather prob, partial loss ----------------
// NOTE: plain stores + separate final reduce. Do NOT use acq_rel agent atomics here:
// round 10 showed they emit per-block L2 writeback/invalidate -> 90 µs (10x regression).
__global__ __launch_bounds__(256) void merge_kernel(const uint32_t* __restrict__ top,
                                                    const float* __restrict__ prob,
                                                    float* __restrict__ partials) {
    __shared__ float red[4];
    const int t = threadIdx.x;
    const int lane = t & 63;
    const int w = t >> 6;
    const int rg = blockIdx.x * 4 + w;             // 0..16383
    const int b = rg >> 12;

    uint4 v4 = ((const uint4*)(top + (size_t)rg * 256))[lane];
    uint32_t v[4] = {v4.x, v4.y, v4.z, v4.w};
    uint32_t m = max(max(v[0], v[1]), max(v[2], v[3]));

    const float* pb = prob + (b << 12);
    float p_r = prob[rg];
    float contrib = 0.f;
#pragma unroll
    for (int k = 0; k < 8; ++k) {
        uint32_t M = m;
#pragma unroll
        for (int off = 32; off; off >>= 1) M = max(M, (uint32_t)__shfl_xor((int)M, off));
        if (lane == k) contrib = fabsf(p_r - pb[M & 0xFFFu]);
#pragma unroll
        for (int s = 0; s < 4; ++s) v[s] = (v[s] == M) ? 0u : v[s];
        m = max(max(v[0], v[1]), max(v[2], v[3]));
    }
#pragma unroll
    for (int off = 32; off; off >>= 1) contrib += __shfl_xor(contrib, off);
    if (lane == 0) red[w] = contrib;
    __syncthreads();
    if (t == 0) partials[blockIdx.x] = red[0] + red[1] + red[2] + red[3];
}

// ---------------- Kernel 4: final reduce (4096 partials) ----------------
__global__ __launch_bounds__(256) void final_kernel(const float* __restrict__ partials,
                                                    float* __restrict__ out) {
    __shared__ float red[256];
    int t = threadIdx.x;
    float s = 0.f;
#pragma unroll
    for (int k = 0; k < 16; ++k) s += partials[k * 256 + t];
    red[t] = s;
    __syncthreads();
    for (int off = 128; off > 0; off >>= 1) {
        if (t < off) red[t] += red[t + off];
        __syncthreads();
    }
    if (t == 0) out[0] = red[0] * (1.f / (B_ * N_ * 8.0f));
}

extern "C" void kernel_launch(void* const* d_in, const int* in_sizes, int n_in,
                              void* d_out, int out_size, void* d_ws, size_t ws_size,
                              hipStream_t stream) {
    const float* feats  = (const float*)d_in[0];
    const float* logits = (const float*)d_in[1];
    float* out = (float*)d_out;
    char* ws = (char*)d_ws;
    _Float16* fn   = (_Float16*)(ws + OFF_FN);
    float* prob    = (float*)(ws + OFF_PROB);
    float* parts   = (float*)(ws + OFF_PART);
    uint32_t* top  = (uint32_t*)(ws + OFF_TOP);

    prep_kernel<<<256, 256, 0, stream>>>(feats, logits, fn, prob);
    gram_sel_t<0><<<B_ * TRI, 256, 0, stream>>>(fn, top);
    merge_kernel<<<4096, 256, 0, stream>>>(top, prob, parts);
    final_kernel<<<1, 256, 0, stream>>>(parts, out);

    // ---- ablation probes (this round only): run AFTER `final`, write only the
    // dead `top` buffer. MODE 1 = GEMM floor; MODE 2 = no row-scan.
    gram_sel_t<1><<<B_ * TRI, 256, 0, stream>>>(fn, top);
    gram_sel_t<2><<<B_ * TRI, 256, 0, stream>>>(fn, top);
}

// Round 9
// 156.729 us; speedup vs baseline: 1.1990x; 1.1990x over previous
//
#include <hip/hip_runtime.h>
#include <hip/hip_bf16.h>

typedef _Float16 half8 __attribute__((ext_vector_type(8)));
typedef unsigned short ushort8 __attribute__((ext_vector_type(8)));
typedef float floatx4 __attribute__((ext_vector_type(4)));

#define B_ 4
#define C_ 256
#define N_ 4096
#define NT 32            // 128-wide tiles per dim
#define TRI 528          // NT*(NT+1)/2 triangular tiles per batch

// workspace layout (bytes)
#define OFF_FN    ((size_t)0)                     // 4*4096*256 fp16 = 8 MB
#define OFF_PROB  ((size_t)(8u << 20))            // 16384 fp32 = 64 KB
#define OFF_PART  (OFF_PROB + 65536)              // 4096 fp32 block partials = 16 KB
#define OFF_TOP   ((size_t)(16u << 20))           // 16384 rows x 32 jtiles x 8 u32 = 16 MB

__device__ __forceinline__ void cas(uint32_t& a, uint32_t& b) {
    uint32_t hi = max(a, b); b = min(a, b); a = hi;
}

// Batcher odd-even mergesort, 8 elems, descending (19 CAS)
__device__ __forceinline__ void sort8(uint32_t v[8]) {
    cas(v[0],v[1]); cas(v[2],v[3]); cas(v[4],v[5]); cas(v[6],v[7]);
    cas(v[0],v[2]); cas(v[1],v[3]); cas(v[4],v[6]); cas(v[5],v[7]);
    cas(v[1],v[2]); cas(v[5],v[6]);
    cas(v[0],v[4]); cas(v[1],v[5]); cas(v[2],v[6]); cas(v[3],v[7]);
    cas(v[2],v[4]); cas(v[3],v[5]);
    cas(v[1],v[2]); cas(v[3],v[4]); cas(v[5],v[6]);
}

// r, n desc-sorted -> r = top-8 of union, desc-sorted (8 max + 12 CAS)
__device__ __forceinline__ void merge8(uint32_t r[8], const uint32_t n[8]) {
    uint32_t m[8];
#pragma unroll
    for (int i = 0; i < 8; ++i) m[i] = max(r[i], n[7 - i]);   // bitonic
    cas(m[0],m[4]); cas(m[1],m[5]); cas(m[2],m[6]); cas(m[3],m[7]);
    cas(m[0],m[2]); cas(m[1],m[3]); cas(m[4],m[6]); cas(m[5],m[7]);
    cas(m[0],m[1]); cas(m[2],m[3]); cas(m[4],m[5]); cas(m[6],m[7]);
#pragma unroll
    for (int i = 0; i < 8; ++i) r[i] = m[i];
}

// ---------------- Kernel 1: fused prep — reads feats once ----------------
#define TS 68
__global__ __launch_bounds__(256) void prep_kernel(const float* __restrict__ feats,
                                                   const float* __restrict__ logits,
                                                   _Float16* __restrict__ fn,
                                                   float* __restrict__ prob) {
    __shared__ __align__(16) float T[C_ * TS];
    __shared__ float S[256];
    __shared__ float I[64];

    const int t  = threadIdx.x;
    const int b  = blockIdx.x >> 6;
    const int i0 = (blockIdx.x & 63) * 64;
    const float* fb = feats + (size_t)b * C_ * N_;

#pragma unroll
    for (int k = 0; k < 16; ++k) {
        int ch = t + k * 256;
        int row = ch >> 4, col4 = ch & 15;
        float4 v = *(const float4*)(fb + (size_t)row * N_ + i0 + col4 * 4);
        *(float4*)&T[row * TS + col4 * 4] = v;
    }
    __syncthreads();
    {
        int i = t & 63, cq = t >> 6;
        float ss = 0.f;
#pragma unroll 8
        for (int j = 0; j < 64; ++j) { float v = T[(cq * 64 + j) * TS + i]; ss += v * v; }
        S[cq * 64 + i] = ss;
    }
    __syncthreads();
    if (t < 64) {
        float ss = S[t] + S[64 + t] + S[128 + t] + S[192 + t];
        I[t] = 1.f / fmaxf(sqrtf(ss), 1e-12f);
        float lg = logits[b * N_ + i0 + t];
        prob[b * N_ + i0 + t] = 1.f / (1.f + expf(-lg));
    }
    __syncthreads();
    {
        int i = t >> 2, chunk = t & 3;
        float s = I[i];
        _Float16* fr = fn + ((size_t)(b * N_ + i0 + i)) * C_ + chunk * 64;
#pragma unroll
        for (int v8 = 0; v8 < 8; ++v8) {
            half8 h;
#pragma unroll
            for (int e = 0; e < 8; ++e)
                h[e] = (_Float16)(T[(chunk * 64 + v8 * 8 + e) * TS + i] * s);
            *(half8*)(fr + v8 * 8) = h;
        }
    }
}

// ---------------- Kernel 2: triangular MFMA gram tile + dual-scan top-8 ----------------
// R7 ablation split: GEMM+dump ~28 µs (2.5x its pipe floor), selection ~18 µs (near
// VALU floor). The GEMM excess is 8 barriers/block convoying all 4 resident blocks
// into lockstep staging stalls (invariant across R0/R1/R2/R5/R6 structures).
// THIS ROUND (resubmit — R8 bench was an infra failure, kernel never ran):
// barrier-free K-loop — A/B fragments loaded DIRECTLY from L2 (no LDS staging).
// Per b128 load, 64 lanes = 16 rows x 4 chunks = 16 fully-consumed 64B lines
// (perfect coalescing). Traffic 256 KB/block (2 waves/panel byte) = 540 MB
// aggregate ~ 15.7 µs at per-XCD L2 BW < current ~24 µs phase. Frag regs identical
// to the ds_read version (arch ~64 VGPR + 64 AGPR acc = 128 -> 4 blocks/CU kept).
// R5's staging(+)read XOR swizzles cancel -> direct chunk = kc*64+kk*32+q*8; same
// K order -> bit-identical. Selection = R0/R5-proven full-tile path, unchanged.
#define CSH 136   // u16 col stride: 272B -> b128-aligned, window starts spread over banks
__global__ __launch_bounds__(256, 4) void gram_sel_kernel(const _Float16* __restrict__ fn,
                                                          uint32_t* __restrict__ top) {
    __shared__ __align__(16) char smem[128 * CSH * 2];   // 34816 B
    unsigned short* Ch = (unsigned short*)smem;          // col-major u16 tile (selection)
    uint32_t* Ms = (uint32_t*)smem;                      // pair-merge staging

    const int t    = threadIdx.x;
    const int lane = t & 63;
    const int w    = t >> 6;
    const int m16  = lane & 15;
    const int q    = lane >> 4;
    const int wm   = w & 1;          // row half (0..1)
    const int wn   = w >> 1;         // col half (0..1)

    // XCD-aware bijective swizzle: grid 2112 = 8 * 264
    const int bid0 = blockIdx.x;
    const int bid  = (bid0 & 7) * 264 + (bid0 >> 3);

    // triangular block index -> (b, it, jt) with it <= jt
    const int b = bid / TRI;
    const int u = bid - b * TRI;
    int it = (int)(32.5f - sqrtf(32.5f * 32.5f - 2.0f * (float)u));
    while (u >= (it + 1) * (65 - (it + 1)) / 2) ++it;
    while (u < it * (65 - it) / 2) --it;
    const int jt = it + (u - it * (65 - it) / 2);
    const bool diag = (it == jt);

    const int i0 = it * 128, j0 = jt * 128;
    const _Float16* fnb = fn + (size_t)b * N_ * C_;

    floatx4 acc[4][4];
#pragma unroll
    for (int mi = 0; mi < 4; ++mi)
#pragma unroll
        for (int ni = 0; ni < 4; ++ni) acc[mi][ni] = floatx4{0.f, 0.f, 0.f, 0.f};

    // barrier-free K-loop: fragments straight from L2 into VGPRs
    const _Float16* pA = fnb + (size_t)(i0 + wm * 64 + m16) * C_ + q * 8;
    const _Float16* pB = fnb + (size_t)(j0 + wn * 64 + m16) * C_ + q * 8;

    for (int kc = 0; kc < 4; ++kc) {
#pragma unroll
        for (int kk = 0; kk < 2; ++kk) {
            const int ko = kc * 64 + kk * 32;    // + q*8 baked into pA/pB
            half8 af[4], bf[4];
#pragma unroll
            for (int mi = 0; mi < 4; ++mi)
                af[mi] = *(const half8*)(pA + (size_t)(mi * 16) * C_ + ko);
#pragma unroll
            for (int ni = 0; ni < 4; ++ni)
                bf[ni] = *(const half8*)(pB + (size_t)(ni * 16) * C_ + ko);
#pragma unroll
            for (int mi = 0; mi < 4; ++mi)
#pragma unroll
                for (int ni = 0; ni < 4; ++ni)
                    acc[mi][ni] = __builtin_amdgcn_mfma_f32_16x16x32_f16(af[mi], bf[ni], acc[mi][ni], 0, 0, 0);
        }
    }

    // ---- dump tile col-major as flipped u16, paired rows via cvt_pkrtz ----
    // C/D layout: col = wn*64 + ni*16 + m16, rows = wm*64 + mi*16 + q*4 + {0..3}
#pragma unroll
    for (int ni = 0; ni < 4; ++ni)
#pragma unroll
        for (int mi = 0; mi < 4; ++mi) {
            const int col = wn * 64 + ni * 16 + m16;
            const int row = wm * 64 + mi * 16 + q * 4;
#pragma unroll
            for (int p = 0; p < 2; ++p) {
                auto pk2 = __builtin_amdgcn_cvt_pkrtz(acc[mi][ni][2 * p], acc[mi][ni][2 * p + 1]);
                uint32_t bits = __builtin_bit_cast(uint32_t, pk2);
                uint32_t s = (bits >> 15) & 0x00010001u;
                uint32_t fl = bits ^ (s * 0x7FFFu + 0x80008000u);   // per-half order-flip
                *(uint32_t*)&Ch[col * CSH + row + 2 * p] = fl;
            }
        }
    __syncthreads();

    // ---- contiguous col-scan (always): 2 threads/col, 64 rows each, b128 reads ----
    // packed idx = global ROW index. Off-diag: j-side partials; diag: == row result.
    uint32_t cpk[8], rpk[8];
    {
        const int ccol = t >> 1, cr0 = (t & 1) * 64;
        const unsigned short* cc = &Ch[ccol * CSH + cr0];
        const int ibase = i0 + cr0;
#pragma unroll
        for (int g = 0; g < 8; ++g) {
            ushort8 v = *(const ushort8*)(cc + g * 8);
            uint32_t cand[8];
#pragma unroll
            for (int e = 0; e < 8; ++e)
                cand[e] = ((uint32_t)v[e] << 16) | (uint32_t)(ibase + g * 8 + e);
            sort8(cand);
            if (g == 0) {
#pragma unroll
                for (int s = 0; s < 8; ++s) cpk[s] = cand[s];
            } else merge8(cpk, cand);
        }
    }
    // ---- strided row-scan (off-diag only): 2 threads/row, 64 cols each ----
    if (!diag) {
        const int rrow = t >> 1, ch0 = (t & 1) * 64;
        const unsigned short* cr = &Ch[ch0 * CSH + rrow];
        const int jbase = j0 + ch0;
#pragma unroll
        for (int g = 0; g < 8; ++g) {
            uint32_t cand[8];
#pragma unroll
            for (int e = 0; e < 8; ++e)
                cand[e] = ((uint32_t)cr[(g * 8 + e) * CSH] << 16) | (uint32_t)(jbase + g * 8 + e);
            sort8(cand);
            if (g == 0) {
#pragma unroll
                for (int s = 0; s < 8; ++s) rpk[s] = cand[s];
            } else merge8(rpk, cand);
        }
    }
    __syncthreads();   // done reading Ch; reuse as merge staging

    // ---- pair-merge across the 2 threads of each col/row, emit 8 u32 ----
    if (t & 1) {
#pragma unroll
        for (int s = 0; s < 8; ++s) Ms[(t >> 1) * 8 + s] = cpk[s];
        if (!diag) {
#pragma unroll
            for (int s = 0; s < 8; ++s) Ms[1024 + (t >> 1) * 8 + s] = rpk[s];
        }
    }
    __syncthreads();
    if (!(t & 1)) {
        uint32_t o[8];
#pragma unroll
        for (int s = 0; s < 8; ++s) o[s] = Ms[(t >> 1) * 8 + s];
        merge8(cpk, o);
        uint32_t* dst = top + (((size_t)b * N_ + j0 + (t >> 1)) * 32 + it) * 8;
        *(uint4*)dst       = make_uint4(cpk[0], cpk[1], cpk[2], cpk[3]);
        *(uint4*)(dst + 4) = make_uint4(cpk[4], cpk[5], cpk[6], cpk[7]);
        if (!diag) {
#pragma unroll
            for (int s = 0; s < 8; ++s) o[s] = Ms[1024 + (t >> 1) * 8 + s];
            merge8(rpk, o);
            uint32_t* dst2 = top + (((size_t)b * N_ + i0 + (t >> 1)) * 32 + jt) * 8;
            *(uint4*)dst2       = make_uint4(rpk[0], rpk[1], rpk[2], rpk[3]);
            *(uint4*)(dst2 + 4) = make_uint4(rpk[4], rpk[5], rpk[6], rpk[7]);
        }
    }
}

// ---------------- Kernel 3: merge 32 partials/row, gather prob, partial loss ----------------
// NOTE: plain stores + separate final reduce. Do NOT use acq_rel agent atomics here:
// round 10 showed they emit per-block L2 writeback/invalidate -> 90 µs (10x regression).
__global__ __launch_bounds__(256) void merge_kernel(const uint32_t* __restrict__ top,
                                                    const float* __restrict__ prob,
                                                    float* __restrict__ partials) {
    __shared__ float red[4];
    const int t = threadIdx.x;
    const int lane = t & 63;
    const int w = t >> 6;
    const int rg = blockIdx.x * 4 + w;             // 0..16383
    const int b = rg >> 12;

    uint4 v4 = ((const uint4*)(top + (size_t)rg * 256))[lane];
    uint32_t v[4] = {v4.x, v4.y, v4.z, v4.w};
    uint32_t m = max(max(v[0], v[1]), max(v[2], v[3]));

    const float* pb = prob + (b << 12);
    float p_r = prob[rg];
    float contrib = 0.f;
#pragma unroll
    for (int k = 0; k < 8; ++k) {
        uint32_t M = m;
#pragma unroll
        for (int off = 32; off; off >>= 1) M = max(M, (uint32_t)__shfl_xor((int)M, off));
        if (lane == k) contrib = fabsf(p_r - pb[M & 0xFFFu]);
#pragma unroll
        for (int s = 0; s < 4; ++s) v[s] = (v[s] == M) ? 0u : v[s];
        m = max(max(v[0], v[1]), max(v[2], v[3]));
    }
#pragma unroll
    for (int off = 32; off; off >>= 1) contrib += __shfl_xor(contrib, off);
    if (lane == 0) red[w] = contrib;
    __syncthreads();
    if (t == 0) partials[blockIdx.x] = red[0] + red[1] + red[2] + red[3];
}

// ---------------- Kernel 4: final reduce (4096 partials) ----------------
__global__ __launch_bounds__(256) void final_kernel(const float* __restrict__ partials,
                                                    float* __restrict__ out) {
    __shared__ float red[256];
    int t = threadIdx.x;
    float s = 0.f;
#pragma unroll
    for (int k = 0; k < 16; ++k) s += partials[k * 256 + t];
    red[t] = s;
    __syncthreads();
    for (int off = 128; off > 0; off >>= 1) {
        if (t < off) red[t] += red[t + off];
        __syncthreads();
    }
    if (t == 0) out[0] = red[0] * (1.f / (B_ * N_ * 8.0f));
}

extern "C" void kernel_launch(void* const* d_in, const int* in_sizes, int n_in,
                              void* d_out, int out_size, void* d_ws, size_t ws_size,
                              hipStream_t stream) {
    const float* feats  = (const float*)d_in[0];
    const float* logits = (const float*)d_in[1];
    float* out = (float*)d_out;
    char* ws = (char*)d_ws;
    _Float16* fn   = (_Float16*)(ws + OFF_FN);
    float* prob    = (float*)(ws + OFF_PROB);
    float* parts   = (float*)(ws + OFF_PART);
    uint32_t* top  = (uint32_t*)(ws + OFF_TOP);

    prep_kernel<<<256, 256, 0, stream>>>(feats, logits, fn, prob);
    gram_sel_kernel<<<B_ * TRI, 256, 0, stream>>>(fn, top);
    merge_kernel<<<4096, 256, 0, stream>>>(top, prob, parts);
    final_kernel<<<1, 256, 0, stream>>>(parts, out);
}

// Round 10
// 128.675 us; speedup vs baseline: 1.4604x; 1.2180x over previous
//
#include <hip/hip_runtime.h>
#include <hip/hip_bf16.h>

typedef _Float16 half8 __attribute__((ext_vector_type(8)));
typedef unsigned short ushort8 __attribute__((ext_vector_type(8)));
typedef float floatx4 __attribute__((ext_vector_type(4)));

#define B_ 4
#define C_ 256
#define N_ 4096
#define NT 32            // 128-wide tiles per dim
#define TRI 528          // NT*(NT+1)/2 triangular tiles per batch

// workspace layout (bytes)
#define OFF_FN    ((size_t)0)                     // 4*4096*256 fp16 = 8 MB
#define OFF_PROB  ((size_t)(8u << 20))            // 16384 fp32 = 64 KB
#define OFF_PART  (OFF_PROB + 65536)              // 4096 fp32 block partials = 16 KB
#define OFF_TOP   ((size_t)(16u << 20))           // 16384 rows x 32 jtiles x 8 u32 = 16 MB

__device__ __forceinline__ void gl_lds16(const void* g, void* l) {
    __builtin_amdgcn_global_load_lds(
        (const __attribute__((address_space(1))) void*)g,
        (__attribute__((address_space(3))) void*)l,
        16, 0, 0);
}

__device__ __forceinline__ void cas(uint32_t& a, uint32_t& b) {
    uint32_t hi = max(a, b); b = min(a, b); a = hi;
}

// Batcher odd-even mergesort, 8 elems, descending (19 CAS)
__device__ __forceinline__ void sort8(uint32_t v[8]) {
    cas(v[0],v[1]); cas(v[2],v[3]); cas(v[4],v[5]); cas(v[6],v[7]);
    cas(v[0],v[2]); cas(v[1],v[3]); cas(v[4],v[6]); cas(v[5],v[7]);
    cas(v[1],v[2]); cas(v[5],v[6]);
    cas(v[0],v[4]); cas(v[1],v[5]); cas(v[2],v[6]); cas(v[3],v[7]);
    cas(v[2],v[4]); cas(v[3],v[5]);
    cas(v[1],v[2]); cas(v[3],v[4]); cas(v[5],v[6]);
}

// r, n desc-sorted -> r = top-8 of union, desc-sorted (8 max + 12 CAS)
__device__ __forceinline__ void merge8(uint32_t r[8], const uint32_t n[8]) {
    uint32_t m[8];
#pragma unroll
    for (int i = 0; i < 8; ++i) m[i] = max(r[i], n[7 - i]);   // bitonic
    cas(m[0],m[4]); cas(m[1],m[5]); cas(m[2],m[6]); cas(m[3],m[7]);
    cas(m[0],m[2]); cas(m[1],m[3]); cas(m[4],m[6]); cas(m[5],m[7]);
    cas(m[0],m[1]); cas(m[2],m[3]); cas(m[4],m[5]); cas(m[6],m[7]);
#pragma unroll
    for (int i = 0; i < 8; ++i) r[i] = m[i];
}

// ---------------- Kernel 1: fused prep — reads feats once ----------------
#define TS 68
__global__ __launch_bounds__(256) void prep_kernel(const float* __restrict__ feats,
                                                   const float* __restrict__ logits,
                                                   _Float16* __restrict__ fn,
                                                   float* __restrict__ prob) {
    __shared__ __align__(16) float T[C_ * TS];
    __shared__ float S[256];
    __shared__ float I[64];

    const int t  = threadIdx.x;
    const int b  = blockIdx.x >> 6;
    const int i0 = (blockIdx.x & 63) * 64;
    const float* fb = feats + (size_t)b * C_ * N_;

#pragma unroll
    for (int k = 0; k < 16; ++k) {
        int ch = t + k * 256;
        int row = ch >> 4, col4 = ch & 15;
        float4 v = *(const float4*)(fb + (size_t)row * N_ + i0 + col4 * 4);
        *(float4*)&T[row * TS + col4 * 4] = v;
    }
    __syncthreads();
    {
        int i = t & 63, cq = t >> 6;
        float ss = 0.f;
#pragma unroll 8
        for (int j = 0; j < 64; ++j) { float v = T[(cq * 64 + j) * TS + i]; ss += v * v; }
        S[cq * 64 + i] = ss;
    }
    __syncthreads();
    if (t < 64) {
        float ss = S[t] + S[64 + t] + S[128 + t] + S[192 + t];
        I[t] = 1.f / fmaxf(sqrtf(ss), 1e-12f);
        float lg = logits[b * N_ + i0 + t];
        prob[b * N_ + i0 + t] = 1.f / (1.f + expf(-lg));
    }
    __syncthreads();
    {
        int i = t >> 2, chunk = t & 3;
        float s = I[i];
        _Float16* fr = fn + ((size_t)(b * N_ + i0 + i)) * C_ + chunk * 64;
#pragma unroll
        for (int v8 = 0; v8 < 8; ++v8) {
            half8 h;
#pragma unroll
            for (int e = 0; e < 8; ++e)
                h[e] = (_Float16)(T[(chunk * 64 + v8 * 8 + e) * TS + i] * s);
            *(half8*)(fr + v8 * 8) = h;
        }
    }
}

// ---------------- Kernel 2: triangular MFMA gram tile + dual-scan top-8 ----------------
// R9 lesson: direct-L2 fragments = 16-line strided transactions -> 80 µs. LDS staging
// is the layout converter and must stay. THIS ROUND: keep staging, DELETE the barriers.
// Wave-PRIVATE staging: each wave gl_lds's its own A-half + B-half (BK=32: 4KB+4KB)
// into a private 8KB LDS slice (4 waves x 8KB = 32KB, same envelope). No __syncthreads
// in the K-loop; per-wave vmcnt(0)/lgkmcnt(0) self-sync; prefetch step s+1 after step
// s's ds_reads retire (MFMAs cover the L2 latency). Waves desync -> no L2 convoy.
// Cost: each half loaded by 2 waves -> 2x L2 traffic (540MB, ~16µs at µbench BW; R5
// ran at only ~10 TB/s effective so headroom exists). Staging lines stay dense
// (16 rows x 64B per gl_lds). R2-proven row-pair XOR slot swizzle -> 2-way (free)
// ds_reads. Same K-chunk order -> bit-identical. Dump/selection = R5 verbatim.
#define CSH 136   // u16 col stride: 272B -> b128-aligned, window starts spread over banks
__global__ __launch_bounds__(256, 4) void gram_sel_kernel(const _Float16* __restrict__ fn,
                                                          uint32_t* __restrict__ top) {
    __shared__ __align__(16) char smem[128 * CSH * 2];   // 34816 B (K-loop uses 32768)
    unsigned short* Ch = (unsigned short*)smem;          // col-major u16 tile (selection)
    uint32_t* Ms = (uint32_t*)smem;                      // pair-merge staging

    const int t    = threadIdx.x;
    const int lane = t & 63;
    const int w    = t >> 6;
    const int m16  = lane & 15;
    const int q    = lane >> 4;
    const int wm   = w & 1;          // row half (0..1)
    const int wn   = w >> 1;         // col half (0..1)

    // XCD-aware bijective swizzle: grid 2112 = 8 * 264
    const int bid0 = blockIdx.x;
    const int bid  = (bid0 & 7) * 264 + (bid0 >> 3);

    // triangular block index -> (b, it, jt) with it <= jt
    const int b = bid / TRI;
    const int u = bid - b * TRI;
    int it = (int)(32.5f - sqrtf(32.5f * 32.5f - 2.0f * (float)u));
    while (u >= (it + 1) * (65 - (it + 1)) / 2) ++it;
    while (u < it * (65 - it) / 2) --it;
    const int jt = it + (u - it * (65 - it) / 2);
    const bool diag = (it == jt);

    const int i0 = it * 128, j0 = jt * 128;
    const _Float16* fnb = fn + (size_t)b * N_ * C_;

    floatx4 acc[4][4];
#pragma unroll
    for (int mi = 0; mi < 4; ++mi)
#pragma unroll
        for (int ni = 0; ni < 4; ++ni) acc[mi][ni] = floatx4{0.f, 0.f, 0.f, 0.f};

    // ---- wave-private staging geometry ----
    // Private slice: A @ priv[0..4096), B @ priv[4096..8192). 128B line = row-pair
    // x 4 chunks(16B); slot = ((row&1)<<2 | q) ^ (L&7), L = row_local>>1.
    // Staging writes are linear (lane*16); the INVERSE permutation is applied on the
    // per-lane global source (rule #21). Note (L&7) == lane>>3 for every inst.
    char* priv = smem + w * 8192;
    const int s8  = lane & 7;
    const int lg3 = lane >> 3;
    const int slg = s8 ^ lg3;
    const int spar = slg >> 2;           // row parity
    const int sq   = slg & 3;            // k-chunk (8 halves)
    const _Float16* gA0 = fnb + (size_t)(i0 + wm * 64 + 2 * lg3 + spar) * C_ + sq * 8;
    const _Float16* gB0 = fnb + (size_t)(j0 + wn * 64 + 2 * lg3 + spar) * C_ + sq * 8;

    auto stagep = [&](int kc8) {
#pragma unroll
        for (int i2 = 0; i2 < 4; ++i2) {
            gl_lds16(gA0 + (size_t)(16 * i2) * C_ + kc8 * 32, priv + i2 * 1024 + lane * 16);
            gl_lds16(gB0 + (size_t)(16 * i2) * C_ + kc8 * 32, priv + 4096 + i2 * 1024 + lane * 16);
        }
    };

    stagep(0);
#pragma unroll
    for (int s = 0; s < 8; ++s) {
        // my private buffer's loads have landed (wave-local wait, no barrier)
        asm volatile("s_waitcnt vmcnt(0)" ::: "memory");
        __builtin_amdgcn_sched_barrier(0);
        half8 af[4], bf[4];
#pragma unroll
        for (int mi = 0; mi < 4; ++mi) {
            const int rl = mi * 16 + m16;
            const int L = rl >> 1;
            const int slot = ((((rl & 1) << 2) | q) ^ (L & 7));
            af[mi] = *(const half8*)(priv + L * 128 + slot * 16);
            bf[mi] = *(const half8*)(priv + 4096 + L * 128 + slot * 16);
        }
        __builtin_amdgcn_sched_barrier(0);
        asm volatile("s_waitcnt lgkmcnt(0)" ::: "memory");   // reads retired -> buffer free
        __builtin_amdgcn_sched_barrier(0);
        if (s < 7) stagep(s + 1);                            // prefetch flies over MFMAs
        __builtin_amdgcn_sched_barrier(0);
#pragma unroll
        for (int mi = 0; mi < 4; ++mi)
#pragma unroll
            for (int ni = 0; ni < 4; ++ni)
                acc[mi][ni] = __builtin_amdgcn_mfma_f32_16x16x32_f16(af[mi], bf[ni], acc[mi][ni], 0, 0, 0);
    }
    __syncthreads();   // K-loop done; smem becomes the selection tile

    // ---- dump tile col-major as flipped u16, paired rows via cvt_pkrtz ----
    // C/D layout: col = wn*64 + ni*16 + m16, rows = wm*64 + mi*16 + q*4 + {0..3}
#pragma unroll
    for (int ni = 0; ni < 4; ++ni)
#pragma unroll
        for (int mi = 0; mi < 4; ++mi) {
            const int col = wn * 64 + ni * 16 + m16;
            const int row = wm * 64 + mi * 16 + q * 4;
#pragma unroll
            for (int p = 0; p < 2; ++p) {
                auto pk2 = __builtin_amdgcn_cvt_pkrtz(acc[mi][ni][2 * p], acc[mi][ni][2 * p + 1]);
                uint32_t bits = __builtin_bit_cast(uint32_t, pk2);
                uint32_t s = (bits >> 15) & 0x00010001u;
                uint32_t fl = bits ^ (s * 0x7FFFu + 0x80008000u);   // per-half order-flip
                *(uint32_t*)&Ch[col * CSH + row + 2 * p] = fl;
            }
        }
    __syncthreads();

    // ---- contiguous col-scan (always): 2 threads/col, 64 rows each, b128 reads ----
    // packed idx = global ROW index. Off-diag: j-side partials; diag: == row result.
    uint32_t cpk[8], rpk[8];
    {
        const int ccol = t >> 1, cr0 = (t & 1) * 64;
        const unsigned short* cc = &Ch[ccol * CSH + cr0];
        const int ibase = i0 + cr0;
#pragma unroll
        for (int g = 0; g < 8; ++g) {
            ushort8 v = *(const ushort8*)(cc + g * 8);
            uint32_t cand[8];
#pragma unroll
            for (int e = 0; e < 8; ++e)
                cand[e] = ((uint32_t)v[e] << 16) | (uint32_t)(ibase + g * 8 + e);
            sort8(cand);
            if (g == 0) {
#pragma unroll
                for (int s = 0; s < 8; ++s) cpk[s] = cand[s];
            } else merge8(cpk, cand);
        }
    }
    // ---- strided row-scan (off-diag only): 2 threads/row, 64 cols each ----
    if (!diag) {
        const int rrow = t >> 1, ch0 = (t & 1) * 64;
        const unsigned short* cr = &Ch[ch0 * CSH + rrow];
        const int jbase = j0 + ch0;
#pragma unroll
        for (int g = 0; g < 8; ++g) {
            uint32_t cand[8];
#pragma unroll
            for (int e = 0; e < 8; ++e)
                cand[e] = ((uint32_t)cr[(g * 8 + e) * CSH] << 16) | (uint32_t)(jbase + g * 8 + e);
            sort8(cand);
            if (g == 0) {
#pragma unroll
                for (int s = 0; s < 8; ++s) rpk[s] = cand[s];
            } else merge8(rpk, cand);
        }
    }
    __syncthreads();   // done reading Ch; reuse as merge staging

    // ---- pair-merge across the 2 threads of each col/row, emit 8 u32 ----
    if (t & 1) {
#pragma unroll
        for (int s = 0; s < 8; ++s) Ms[(t >> 1) * 8 + s] = cpk[s];
        if (!diag) {
#pragma unroll
            for (int s = 0; s < 8; ++s) Ms[1024 + (t >> 1) * 8 + s] = rpk[s];
        }
    }
    __syncthreads();
    if (!(t & 1)) {
        uint32_t o[8];
#pragma unroll
        for (int s = 0; s < 8; ++s) o[s] = Ms[(t >> 1) * 8 + s];
        merge8(cpk, o);
        uint32_t* dst = top + (((size_t)b * N_ + j0 + (t >> 1)) * 32 + it) * 8;
        *(uint4*)dst       = make_uint4(cpk[0], cpk[1], cpk[2], cpk[3]);
        *(uint4*)(dst + 4) = make_uint4(cpk[4], cpk[5], cpk[6], cpk[7]);
        if (!diag) {
#pragma unroll
            for (int s = 0; s < 8; ++s) o[s] = Ms[1024 + (t >> 1) * 8 + s];
            merge8(rpk, o);
            uint32_t* dst2 = top + (((size_t)b * N_ + i0 + (t >> 1)) * 32 + jt) * 8;
            *(uint4*)dst2       = make_uint4(rpk[0], rpk[1], rpk[2], rpk[3]);
            *(uint4*)(dst2 + 4) = make_uint4(rpk[4], rpk[5], rpk[6], rpk[7]);
        }
    }
}

// ---------------- Kernel 3: merge 32 partials/row, gather prob, partial loss ----------------
// NOTE: plain stores + separate final reduce. Do NOT use acq_rel agent atomics here:
// round 10 showed they emit per-block L2 writeback/invalidate -> 90 µs (10x regression).
__global__ __launch_bounds__(256) void merge_kernel(const uint32_t* __restrict__ top,
                                                    const float* __restrict__ prob,
                                                    float* __restrict__ partials) {
    __shared__ float red[4];
    const int t = threadIdx.x;
    const int lane = t & 63;
    const int w = t >> 6;
    const int rg = blockIdx.x * 4 + w;             // 0..16383
    const int b = rg >> 12;

    uint4 v4 = ((const uint4*)(top + (size_t)rg * 256))[lane];
    uint32_t v[4] = {v4.x, v4.y, v4.z, v4.w};
    uint32_t m = max(max(v[0], v[1]), max(v[2], v[3]));

    const float* pb = prob + (b << 12);
    float p_r = prob[rg];
    float contrib = 0.f;
#pragma unroll
    for (int k = 0; k < 8; ++k) {
        uint32_t M = m;
#pragma unroll
        for (int off = 32; off; off >>= 1) M = max(M, (uint32_t)__shfl_xor((int)M, off));
        if (lane == k) contrib = fabsf(p_r - pb[M & 0xFFFu]);
#pragma unroll
        for (int s = 0; s < 4; ++s) v[s] = (v[s] == M) ? 0u : v[s];
        m = max(max(v[0], v[1]), max(v[2], v[3]));
    }
#pragma unroll
    for (int off = 32; off; off >>= 1) contrib += __shfl_xor(contrib, off);
    if (lane == 0) red[w] = contrib;
    __syncthreads();
    if (t == 0) partials[blockIdx.x] = red[0] + red[1] + red[2] + red[3];
}

// ---------------- Kernel 4: final reduce (4096 partials) ----------------
__global__ __launch_bounds__(256) void final_kernel(const float* __restrict__ partials,
                                                    float* __restrict__ out) {
    __shared__ float red[256];
    int t = threadIdx.x;
    float s = 0.f;
#pragma unroll
    for (int k = 0; k < 16; ++k) s += partials[k * 256 + t];
    red[t] = s;
    __syncthreads();
    for (int off = 128; off > 0; off >>= 1) {
        if (t < off) red[t] += red[t + off];
        __syncthreads();
    }
    if (t == 0) out[0] = red[0] * (1.f / (B_ * N_ * 8.0f));
}

extern "C" void kernel_launch(void* const* d_in, const int* in_sizes, int n_in,
                              void* d_out, int out_size, void* d_ws, size_t ws_size,
                              hipStream_t stream) {
    const float* feats  = (const float*)d_in[0];
    const float* logits = (const float*)d_in[1];
    float* out = (float*)d_out;
    char* ws = (char*)d_ws;
    _Float16* fn   = (_Float16*)(ws + OFF_FN);
    float* prob    = (float*)(ws + OFF_PROB);
    float* parts   = (float*)(ws + OFF_PART);
    uint32_t* top  = (uint32_t*)(ws + OFF_TOP);

    prep_kernel<<<256, 256, 0, stream>>>(feats, logits, fn, prob);
    gram_sel_kernel<<<B_ * TRI, 256, 0, stream>>>(fn, top);
    merge_kernel<<<4096, 256, 0, stream>>>(top, prob, parts);
    final_kernel<<<1, 256, 0, stream>>>(parts, out);
}

// Round 11
// 128.026 us; speedup vs baseline: 1.4679x; 1.0051x over previous
//
#include <hip/hip_runtime.h>
#include <hip/hip_bf16.h>

typedef _Float16 half8 __attribute__((ext_vector_type(8)));
typedef unsigned short ushort8 __attribute__((ext_vector_type(8)));
typedef float floatx4 __attribute__((ext_vector_type(4)));

#define B_ 4
#define C_ 256
#define N_ 4096
#define NT 32            // 128-wide tiles per dim
#define TRI 528          // NT*(NT+1)/2 triangular tiles per batch

// workspace layout (bytes)
#define OFF_FN    ((size_t)0)                     // 4*4096*256 fp16 = 8 MB
#define OFF_PROB  ((size_t)(8u << 20))            // 16384 fp32 = 64 KB
#define OFF_PART  (OFF_PROB + 65536)              // 4096 fp32 block partials = 16 KB
#define OFF_TOP   ((size_t)(16u << 20))           // 16384 rows x 32 jtiles x 8 u32 = 16 MB

__device__ __forceinline__ void gl_lds16(const void* g, void* l) {
    __builtin_amdgcn_global_load_lds(
        (const __attribute__((address_space(1))) void*)g,
        (__attribute__((address_space(3))) void*)l,
        16, 0, 0);
}

__device__ __forceinline__ void cas(uint32_t& a, uint32_t& b) {
    uint32_t hi = max(a, b); b = min(a, b); a = hi;
}

// Batcher odd-even mergesort, 8 elems, descending (19 CAS)
__device__ __forceinline__ void sort8(uint32_t v[8]) {
    cas(v[0],v[1]); cas(v[2],v[3]); cas(v[4],v[5]); cas(v[6],v[7]);
    cas(v[0],v[2]); cas(v[1],v[3]); cas(v[4],v[6]); cas(v[5],v[7]);
    cas(v[1],v[2]); cas(v[5],v[6]);
    cas(v[0],v[4]); cas(v[1],v[5]); cas(v[2],v[6]); cas(v[3],v[7]);
    cas(v[2],v[4]); cas(v[3],v[5]);
    cas(v[1],v[2]); cas(v[3],v[4]); cas(v[5],v[6]);
}

// r, n desc-sorted -> r = top-8 of union, desc-sorted (8 max + 12 CAS)
__device__ __forceinline__ void merge8(uint32_t r[8], const uint32_t n[8]) {
    uint32_t m[8];
#pragma unroll
    for (int i = 0; i < 8; ++i) m[i] = max(r[i], n[7 - i]);   // bitonic
    cas(m[0],m[4]); cas(m[1],m[5]); cas(m[2],m[6]); cas(m[3],m[7]);
    cas(m[0],m[2]); cas(m[1],m[3]); cas(m[4],m[6]); cas(m[5],m[7]);
    cas(m[0],m[1]); cas(m[2],m[3]); cas(m[4],m[5]); cas(m[6],m[7]);
#pragma unroll
    for (int i = 0; i < 8; ++i) r[i] = m[i];
}

// ---------------- Kernel 1: fused prep — reads feats once ----------------
#define TS 68
__global__ __launch_bounds__(256) void prep_kernel(const float* __restrict__ feats,
                                                   const float* __restrict__ logits,
                                                   _Float16* __restrict__ fn,
                                                   float* __restrict__ prob) {
    __shared__ __align__(16) float T[C_ * TS];
    __shared__ float S[256];
    __shared__ float I[64];

    const int t  = threadIdx.x;
    const int b  = blockIdx.x >> 6;
    const int i0 = (blockIdx.x & 63) * 64;
    const float* fb = feats + (size_t)b * C_ * N_;

#pragma unroll
    for (int k = 0; k < 16; ++k) {
        int ch = t + k * 256;
        int row = ch >> 4, col4 = ch & 15;
        float4 v = *(const float4*)(fb + (size_t)row * N_ + i0 + col4 * 4);
        *(float4*)&T[row * TS + col4 * 4] = v;
    }
    __syncthreads();
    {
        int i = t & 63, cq = t >> 6;
        float ss = 0.f;
#pragma unroll 8
        for (int j = 0; j < 64; ++j) { float v = T[(cq * 64 + j) * TS + i]; ss += v * v; }
        S[cq * 64 + i] = ss;
    }
    __syncthreads();
    if (t < 64) {
        float ss = S[t] + S[64 + t] + S[128 + t] + S[192 + t];
        I[t] = 1.f / fmaxf(sqrtf(ss), 1e-12f);
        float lg = logits[b * N_ + i0 + t];
        prob[b * N_ + i0 + t] = 1.f / (1.f + expf(-lg));
    }
    __syncthreads();
    {
        int i = t >> 2, chunk = t & 3;
        float s = I[i];
        _Float16* fr = fn + ((size_t)(b * N_ + i0 + i)) * C_ + chunk * 64;
#pragma unroll
        for (int v8 = 0; v8 < 8; ++v8) {
            half8 h;
#pragma unroll
            for (int e = 0; e < 8; ++e)
                h[e] = (_Float16)(T[(chunk * 64 + v8 * 8 + e) * TS + i] * s);
            *(half8*)(fr + v8 * 8) = h;
        }
    }
}

// ---------------- Kernel 2: triangular MFMA gram tile + dual-scan top-8 ----------------
// FINAL STRUCTURE (session best, R5 = 45.2 µs): BK=64 single-buffer K-loop with
// __syncthreads staging, 64x64 wave quadrants (4 A + 4 B ds_read_b128 feed 16 MFMAs),
// XCD swizzle (FETCH 34.4 -> 7.1 MB). Structural alternatives measured and ranked:
//   45.2 this | 46.1 counted-vmcnt BK=32 dbuf (R6) | 48.6 block BK=32 dbuf (R1)
// | 52.3 wave-private barrier-free (R10) | 79.9 direct-L2 fragments (R9).
// Occupancy is register-capped at 4 blocks/CU (64 arch VGPR + 64 AGPR acc = 128/wave;
// R4: forcing 5 blocks spills acc -> 81 MB scratch writes). R7 ablation: GEMM+dump
// ~28 µs, selection ~18 µs (near its VALU-op floor).
#define CSH 136   // u16 col stride: 272B -> b128-aligned, window starts spread over banks
__global__ __launch_bounds__(256, 4) void gram_sel_kernel(const _Float16* __restrict__ fn,
                                                          uint32_t* __restrict__ top) {
    __shared__ __align__(16) char smem[128 * CSH * 2];   // 34816 B
    _Float16* As = (_Float16*)smem;                      // 16 KB (K-loop)
    _Float16* Bs = (_Float16*)(smem + 16384);            // 16 KB (K-loop)
    unsigned short* Ch = (unsigned short*)smem;          // col-major u16 tile (selection)
    uint32_t* Ms = (uint32_t*)smem;                      // pair-merge staging

    const int t    = threadIdx.x;
    const int lane = t & 63;
    const int w    = t >> 6;
    const int m16  = lane & 15;
    const int q    = lane >> 4;
    const int wm   = w & 1;          // row half (0..1)
    const int wn   = w >> 1;         // col half (0..1)

    // XCD-aware bijective swizzle: grid 2112 = 8 * 264
    const int bid0 = blockIdx.x;
    const int bid  = (bid0 & 7) * 264 + (bid0 >> 3);

    // triangular block index -> (b, it, jt) with it <= jt
    const int b = bid / TRI;
    const int u = bid - b * TRI;
    int it = (int)(32.5f - sqrtf(32.5f * 32.5f - 2.0f * (float)u));
    while (u >= (it + 1) * (65 - (it + 1)) / 2) ++it;
    while (u < it * (65 - it) / 2) --it;
    const int jt = it + (u - it * (65 - it) / 2);
    const bool diag = (it == jt);

    const int i0 = it * 128, j0 = jt * 128;
    const _Float16* fnb = fn + (size_t)b * N_ * C_;

    const int srowb = t >> 3;
    const int schunk = (t & 7) ^ (srowb & 7);
    const int sw = m16 & 7;

    floatx4 acc[4][4];
#pragma unroll
    for (int mi = 0; mi < 4; ++mi)
#pragma unroll
        for (int ni = 0; ni < 4; ++ni) acc[mi][ni] = floatx4{0.f, 0.f, 0.f, 0.f};

    for (int kc = 0; kc < 4; ++kc) {
#pragma unroll
        for (int r = 0; r < 4; ++r) {
            int row = r * 32 + srowb;
            const _Float16* gA = fnb + (size_t)(i0 + row) * C_ + kc * 64 + schunk * 8;
            const _Float16* gB = fnb + (size_t)(j0 + row) * C_ + kc * 64 + schunk * 8;
            gl_lds16(gA, (char*)As + r * 4096 + t * 16);
            gl_lds16(gB, (char*)Bs + r * 4096 + t * 16);
        }
        __syncthreads();
#pragma unroll
        for (int kk = 0; kk < 2; ++kk) {
            const int ko = ((kk * 4 + q) ^ sw) * 8;
            half8 af[4], bf[4];
#pragma unroll
            for (int mi = 0; mi < 4; ++mi)
                af[mi] = *(const half8*)&As[(wm * 64 + mi * 16 + m16) * 64 + ko];
#pragma unroll
            for (int ni = 0; ni < 4; ++ni)
                bf[ni] = *(const half8*)&Bs[(wn * 64 + ni * 16 + m16) * 64 + ko];
#pragma unroll
            for (int mi = 0; mi < 4; ++mi)
#pragma unroll
                for (int ni = 0; ni < 4; ++ni)
                    acc[mi][ni] = __builtin_amdgcn_mfma_f32_16x16x32_f16(af[mi], bf[ni], acc[mi][ni], 0, 0, 0);
        }
        __syncthreads();
    }

    // ---- dump tile col-major as flipped u16, paired rows via cvt_pkrtz ----
    // C/D layout: col = wn*64 + ni*16 + m16, rows = wm*64 + mi*16 + q*4 + {0..3}
#pragma unroll
    for (int ni = 0; ni < 4; ++ni)
#pragma unroll
        for (int mi = 0; mi < 4; ++mi) {
            const int col = wn * 64 + ni * 16 + m16;
            const int row = wm * 64 + mi * 16 + q * 4;
#pragma unroll
            for (int p = 0; p < 2; ++p) {
                auto pk2 = __builtin_amdgcn_cvt_pkrtz(acc[mi][ni][2 * p], acc[mi][ni][2 * p + 1]);
                uint32_t bits = __builtin_bit_cast(uint32_t, pk2);
                uint32_t s = (bits >> 15) & 0x00010001u;
                uint32_t fl = bits ^ (s * 0x7FFFu + 0x80008000u);   // per-half order-flip
                *(uint32_t*)&Ch[col * CSH + row + 2 * p] = fl;
            }
        }
    __syncthreads();

    // ---- contiguous col-scan (always): 2 threads/col, 64 rows each, b128 reads ----
    // packed idx = global ROW index. Off-diag: j-side partials; diag: == row result.
    uint32_t cpk[8], rpk[8];
    {
        const int ccol = t >> 1, cr0 = (t & 1) * 64;
        const unsigned short* cc = &Ch[ccol * CSH + cr0];
        const int ibase = i0 + cr0;
#pragma unroll
        for (int g = 0; g < 8; ++g) {
            ushort8 v = *(const ushort8*)(cc + g * 8);
            uint32_t cand[8];
#pragma unroll
            for (int e = 0; e < 8; ++e)
                cand[e] = ((uint32_t)v[e] << 16) | (uint32_t)(ibase + g * 8 + e);
            sort8(cand);
            if (g == 0) {
#pragma unroll
                for (int s = 0; s < 8; ++s) cpk[s] = cand[s];
            } else merge8(cpk, cand);
        }
    }
    // ---- strided row-scan (off-diag only): 2 threads/row, 64 cols each ----
    if (!diag) {
        const int rrow = t >> 1, ch0 = (t & 1) * 64;
        const unsigned short* cr = &Ch[ch0 * CSH + rrow];
        const int jbase = j0 + ch0;
#pragma unroll
        for (int g = 0; g < 8; ++g) {
            uint32_t cand[8];
#pragma unroll
            for (int e = 0; e < 8; ++e)
                cand[e] = ((uint32_t)cr[(g * 8 + e) * CSH] << 16) | (uint32_t)(jbase + g * 8 + e);
            sort8(cand);
            if (g == 0) {
#pragma unroll
                for (int s = 0; s < 8; ++s) rpk[s] = cand[s];
            } else merge8(rpk, cand);
        }
    }
    __syncthreads();   // done reading Ch; reuse as merge staging

    // ---- pair-merge across the 2 threads of each col/row, emit 8 u32 ----
    if (t & 1) {
#pragma unroll
        for (int s = 0; s < 8; ++s) Ms[(t >> 1) * 8 + s] = cpk[s];
        if (!diag) {
#pragma unroll
            for (int s = 0; s < 8; ++s) Ms[1024 + (t >> 1) * 8 + s] = rpk[s];
        }
    }
    __syncthreads();
    if (!(t & 1)) {
        uint32_t o[8];
#pragma unroll
        for (int s = 0; s < 8; ++s) o[s] = Ms[(t >> 1) * 8 + s];
        merge8(cpk, o);
        uint32_t* dst = top + (((size_t)b * N_ + j0 + (t >> 1)) * 32 + it) * 8;
        *(uint4*)dst       = make_uint4(cpk[0], cpk[1], cpk[2], cpk[3]);
        *(uint4*)(dst + 4) = make_uint4(cpk[4], cpk[5], cpk[6], cpk[7]);
        if (!diag) {
#pragma unroll
            for (int s = 0; s < 8; ++s) o[s] = Ms[1024 + (t >> 1) * 8 + s];
            merge8(rpk, o);
            uint32_t* dst2 = top + (((size_t)b * N_ + i0 + (t >> 1)) * 32 + jt) * 8;
            *(uint4*)dst2       = make_uint4(rpk[0], rpk[1], rpk[2], rpk[3]);
            *(uint4*)(dst2 + 4) = make_uint4(rpk[4], rpk[5], rpk[6], rpk[7]);
        }
    }
}

// ---------------- Kernel 3: merge 32 partials/row, gather prob, partial loss ----------------
// NOTE: plain stores + separate final reduce. Do NOT use acq_rel agent atomics here:
// round 10 showed they emit per-block L2 writeback/invalidate -> 90 µs (10x regression).
__global__ __launch_bounds__(256) void merge_kernel(const uint32_t* __restrict__ top,
                                                    const float* __restrict__ prob,
                                                    float* __restrict__ partials) {
    __shared__ float red[4];
    const int t = threadIdx.x;
    const int lane = t & 63;
    const int w = t >> 6;
    const int rg = blockIdx.x * 4 + w;             // 0..16383
    const int b = rg >> 12;

    uint4 v4 = ((const uint4*)(top + (size_t)rg * 256))[lane];
    uint32_t v[4] = {v4.x, v4.y, v4.z, v4.w};
    uint32_t m = max(max(v[0], v[1]), max(v[2], v[3]));

    const float* pb = prob + (b << 12);
    float p_r = prob[rg];
    float contrib = 0.f;
#pragma unroll
    for (int k = 0; k < 8; ++k) {
        uint32_t M = m;
#pragma unroll
        for (int off = 32; off; off >>= 1) M = max(M, (uint32_t)__shfl_xor((int)M, off));
        if (lane == k) contrib = fabsf(p_r - pb[M & 0xFFFu]);
#pragma unroll
        for (int s = 0; s < 4; ++s) v[s] = (v[s] == M) ? 0u : v[s];
        m = max(max(v[0], v[1]), max(v[2], v[3]));
    }
#pragma unroll
    for (int off = 32; off; off >>= 1) contrib += __shfl_xor(contrib, off);
    if (lane == 0) red[w] = contrib;
    __syncthreads();
    if (t == 0) partials[blockIdx.x] = red[0] + red[1] + red[2] + red[3];
}

// ---------------- Kernel 4: final reduce (4096 partials) ----------------
__global__ __launch_bounds__(256) void final_kernel(const float* __restrict__ partials,
                                                    float* __restrict__ out) {
    __shared__ float red[256];
    int t = threadIdx.x;
    float s = 0.f;
#pragma unroll
    for (int k = 0; k < 16; ++k) s += partials[k * 256 + t];
    red[t] = s;
    __syncthreads();
    for (int off = 128; off > 0; off >>= 1) {
        if (t < off) red[t] += red[t + off];
        __syncthreads();
    }
    if (t == 0) out[0] = red[0] * (1.f / (B_ * N_ * 8.0f));
}

extern "C" void kernel_launch(void* const* d_in, const int* in_sizes, int n_in,
                              void* d_out, int out_size, void* d_ws, size_t ws_size,
                              hipStream_t stream) {
    const float* feats  = (const float*)d_in[0];
    const float* logits = (const float*)d_in[1];
    float* out = (float*)d_out;
    char* ws = (char*)d_ws;
    _Float16* fn   = (_Float16*)(ws + OFF_FN);
    float* prob    = (float*)(ws + OFF_PROB);
    float* parts   = (float*)(ws + OFF_PART);
    uint32_t* top  = (uint32_t*)(ws + OFF_TOP);

    prep_kernel<<<256, 256, 0, stream>>>(feats, logits, fn, prob);
    gram_sel_kernel<<<B_ * TRI, 256, 0, stream>>>(fn, top);
    merge_kernel<<<4096, 256, 0, stream>>>(top, prob, parts);
    final_kernel<<<1, 256, 0, stream>>>(parts, out);
}